// Round 6
// baseline (1422.912 us; speedup 1.0000x reference)
//
#include <hip/hip_runtime.h>
#include <math.h>

// ---- problem constants ----
constexpr int kHF = 361, kWF = 720;       // full grid
constexpr int kHP = 90,  kWP = 180;       // processor grid
constexpr int kCIN = 26, kCE = 48, kCOUT = 24;
constexpr int kK = 9, kNB = 6;
constexpr int kL = 90, kM = 90;
constexpr int kNL = 4, kHD = 96;
constexpr int kNP  = kHP * kWP;           // 16200
constexpr int kNPF = kHF * kWF;           // 259920

#ifndef M_PI
#define M_PI 3.14159265358979323846
#endif

// ---------------- prep 1: DFT tables + decoder weight transpose ----------------
__global__ __launch_bounds__(256) void k_prep1(float* __restrict__ fc, float* __restrict__ fs,
                                               float* __restrict__ ic, float* __restrict__ isn,
                                               const float* __restrict__ dw, float* __restrict__ dwT) {
    int t = blockIdx.x * 256 + threadIdx.x;
    if (t < kM * kWP) {
        int m = t / kWP, w = t % kWP;
        double th = (2.0 * M_PI / (double)kWP) * (double)(m * w);
        double c = cos(th), s = sin(th);
        fc[w * kM + m] = (float)(c / (double)kWP);
        fs[w * kM + m] = (float)(-s / (double)kWP);
        float sc = (m == 0) ? 1.0f : 2.0f;
        ic[m * kWP + w] = sc * (float)c;
        isn[m * kWP + w] = sc * (float)s;
    }
    if (t < kCOUT * kCE * kK) {
        int k = t % kK;
        int i = (t / kK) % kCE;
        int o = t / (kK * kCE);
        dwT[((size_t)i * kCOUT + o) * kK + k] = dw[t];
    }
}

// ---------------- prep 2: transpose both Legendre matrices ----------------
__global__ __launch_bounds__(256) void k_prep2(const float* __restrict__ Pw, const float* __restrict__ Pi,
                                               float* __restrict__ PwT, float* __restrict__ PiT) {
    int t = blockIdx.x * 256 + threadIdx.x;
    int N = kL * kM * kHP;
    if (t >= 2 * N) return;
    int mode = t >= N ? 1 : 0;
    int u = mode ? t - N : t;
    int l = u / (kM * kHP);
    int r = u % (kM * kHP);
    int m = r / kHP;
    int tt = r % kHP;
    if (mode == 0) PwT[(l * kHP + tt) * kM + m] = Pw[u];
    else           PiT[(tt * kL + l) * kM + m] = Pi[u];
}

// ---------------- disco conv (encoder / processor) ----------------
template <int TCIN, int TCOUT, int OG>
__global__ __launch_bounds__(256) void k_disco(const float* __restrict__ src, int srcStride,
                                               const int* __restrict__ idx, const float* __restrict__ vals,
                                               const float* __restrict__ w, float* __restrict__ out, int np) {
    int gt = blockIdx.x * 256 + threadIdx.x;
    if (gt >= np * OG) return;
    int p = gt % np;
    int og = gt / np;
    constexpr int OC = TCOUT / OG;

    int qi[kNB];
#pragma unroll
    for (int n = 0; n < kNB; n++) qi[n] = idx[p * kNB + n];

    float vv[kK][kNB];
#pragma unroll
    for (int k = 0; k < kK; k++) {
        const float* vp = vals + ((size_t)k * np + p) * kNB;
#pragma unroll
        for (int n = 0; n < kNB; n += 2) {
            float2 v2 = *(const float2*)(vp + n);
            vv[k][n] = v2.x; vv[k][n + 1] = v2.y;
        }
    }

    float acc[OC];
#pragma unroll
    for (int o = 0; o < OC; o++) acc[o] = 0.0f;

    const float* wbase = w + (size_t)og * OC * TCIN * kK;

    for (int i = 0; i < TCIN; i++) {
        float xg[kNB];
#pragma unroll
        for (int n = 0; n < kNB; n++) xg[n] = src[i * srcStride + qi[n]];
        float z[kK];
#pragma unroll
        for (int k = 0; k < kK; k++) {
            float zz = 0.0f;
#pragma unroll
            for (int n = 0; n < kNB; n++) zz = fmaf(vv[k][n], xg[n], zz);
            z[k] = zz;
        }
#pragma unroll
        for (int o = 0; o < OC; o++) {
            const float* wp = wbase + ((size_t)o * TCIN + i) * kK;
            float s = acc[o];
#pragma unroll
            for (int k = 0; k < kK; k++) s = fmaf(wp[k], z[k], s);
            acc[o] = s;
        }
    }
#pragma unroll
    for (int o = 0; o < OC; o++) out[(size_t)(og * OC + o) * np + p] = acc[o];
}

// ---------------- spectral pipeline ----------------
__global__ __launch_bounds__(256) void k_rfft(const float* __restrict__ g, const float* __restrict__ fc,
                                              const float* __restrict__ fs, float* __restrict__ xre,
                                              float* __restrict__ xim) {
    int t = blockIdx.x * 256 + threadIdx.x;
    if (t >= kCE * kHP * kM) return;
    int m = t % kM;
    int row = t / kM;
    const float* gr = g + (size_t)row * kWP;
    float ar = 0.0f, ai = 0.0f;
    for (int w = 0; w < kWP; w++) {
        float gv = gr[w];
        ar = fmaf(gv, fc[w * kM + m], ar);
        ai = fmaf(gv, fs[w * kM + m], ai);
    }
    xre[t] = ar;
    xim[t] = ai;
}

__global__ __launch_bounds__(256) void k_sht(const float* __restrict__ PwT, const float* __restrict__ xre,
                                             const float* __restrict__ xim, float* __restrict__ cre,
                                             float* __restrict__ cim) {
    int t = blockIdx.x * 256 + threadIdx.x;
    if (t >= kCE * kL * kM) return;
    int m = t % kM;
    int l = (t / kM) % kL;
    int c = t / (kM * kL);
    float ar = 0.0f, ai = 0.0f;
    for (int tt = 0; tt < kHP; tt++) {
        float pv = PwT[((size_t)l * kHP + tt) * kM + m];
        ar = fmaf(pv, xre[((size_t)c * kHP + tt) * kM + m], ar);
        ai = fmaf(pv, xim[((size_t)c * kHP + tt) * kM + m], ai);
    }
    cre[t] = ar;
    cim[t] = ai;
}

__global__ __launch_bounds__(256) void k_gmix(const float* __restrict__ gwl, const float* __restrict__ cre,
                                              const float* __restrict__ cim, float* __restrict__ ore,
                                              float* __restrict__ oim) {
    int t = blockIdx.x * 256 + threadIdx.x;
    if (t >= kCE * kL * kM) return;
    int m = t % kM;
    int l = (t / kM) % kL;
    int o = t / (kM * kL);
    float ar = 0.0f, ai = 0.0f;
    for (int i = 0; i < kCE; i++) {
        float gv = gwl[((size_t)o * kCE + i) * kL + l];
        ar = fmaf(gv, cre[((size_t)i * kL + l) * kM + m], ar);
        ai = fmaf(gv, cim[((size_t)i * kL + l) * kM + m], ai);
    }
    ore[t] = ar;
    oim[t] = ai;
}

__global__ __launch_bounds__(256) void k_isht(const float* __restrict__ PiT, const float* __restrict__ cre,
                                              const float* __restrict__ cim, float* __restrict__ xre,
                                              float* __restrict__ xim) {
    int t = blockIdx.x * 256 + threadIdx.x;
    if (t >= kCE * kHP * kM) return;
    int m = t % kM;
    int tt = (t / kM) % kHP;
    int c = t / (kM * kHP);
    float ar = 0.0f, ai = 0.0f;
    for (int l = 0; l < kL; l++) {
        float pv = PiT[((size_t)tt * kL + l) * kM + m];
        ar = fmaf(pv, cre[((size_t)c * kL + l) * kM + m], ar);
        ai = fmaf(pv, cim[((size_t)c * kL + l) * kM + m], ai);
    }
    xre[t] = ar;
    xim[t] = ai;
}

__global__ __launch_bounds__(256) void k_irfft(const float* __restrict__ xre, const float* __restrict__ xim,
                                               const float* __restrict__ ic, const float* __restrict__ isn,
                                               float* __restrict__ dx) {
    int t = blockIdx.x * 256 + threadIdx.x;
    if (t >= kCE * kHP * kWP) return;
    int w = t % kWP;
    int row = t / kWP;
    const float* xr = xre + (size_t)row * kM;
    const float* xi = xim + (size_t)row * kM;
    float a = 0.0f;
    for (int m = 0; m < kM; m++) {
        a = fmaf(xr[m], ic[m * kWP + w], a);
        a = fmaf(-xi[m], isn[m * kWP + w], a);
    }
    dx[t] = a;
}

// ---------------- MLP (split, highly parallel) ----------------
__device__ __forceinline__ float gelu_tanh(float x) {
    float x3 = x * x * x;
    float t = tanhf(0.7978845608028654f * (x + 0.044715f * x3));
    return 0.5f * x * (1.0f + t);
}

__global__ __launch_bounds__(256) void k_mlp1(const float* __restrict__ m1w, const float* __restrict__ dx,
                                              float* __restrict__ dx1) {
    int t = blockIdx.x * 256 + threadIdx.x;
    if (t >= kHD * kNP) return;
    int p = t % kNP;
    int hh = t / kNP;
    float a = 0.0f;
    for (int i = 0; i < kCE; i++) a = fmaf(m1w[hh * kCE + i], dx[(size_t)i * kNP + p], a);
    dx1[t] = gelu_tanh(a);
}

__global__ __launch_bounds__(256) void k_mlp2(const float* __restrict__ m2w, const float* __restrict__ lsw,
                                              const float* __restrict__ dx1, float* __restrict__ h) {
    int t = blockIdx.x * 256 + threadIdx.x;
    if (t >= kCE * kNP) return;
    int p = t % kNP;
    int o = t / kNP;
    float a = 0.0f;
    for (int j = 0; j < kHD; j++) a = fmaf(m2w[o * kHD + j], dx1[(size_t)j * kNP + p], a);
    h[t] = h[t] + lsw[o] * a;
}

// ---------------- decoder: per-point 3x3 stencil, small-LDS high-occupancy ----------------
// out[o,p] is linear in h over a 3-row x 3-col patch (rows F..F+2, cols G..G+2 mod 180).
// Per thread: ck[9][3][3] built once; per channel: 9 LDS reads + 81 + 216 FMA.
// LDS layout hs[q*180 + lon], q = ii*3 + rr: staging writes exactly linear (conflict-
// free); reads are 16 consecutive words per wave with 4-lane broadcast (conflict-free).
constexpr int kT   = 240;   // outputs per block
constexpr int kCH  = 8;     // channel chunk

__global__ __launch_bounds__(256, 4) void k_dconv_s2(const float* __restrict__ h,
                                                     const float* __restrict__ dvals,
                                                     const float* __restrict__ dwT,
                                                     const int* __restrict__ li0, const int* __restrict__ li1,
                                                     const float* __restrict__ lwt, const int* __restrict__ oi0,
                                                     const int* __restrict__ oi1, const float* __restrict__ owt,
                                                     float* __restrict__ out) {
    __shared__ float hs[kCH * 3 * kWP];  // 4320 floats = 17.3 KB

    int blk = blockIdx.x;
    int lat = blk / 3;
    int seg = blk % 3;
    int lon0 = seg * kT;
    int tid = threadIdx.x;
    bool active = tid < kT;
    int p_lon = lon0 + tid;
    int p = lat * kWF + p_lon;

    // ---- latitude: output rows lat-1..lat+1 (clipped) -> patch rows ----
    int i0r[3], i1r[3];
    float awr[3];
#pragma unroll
    for (int r = 0; r < 3; r++) {
        int Lr = lat - 1 + r;
        Lr = Lr < 0 ? 0 : (Lr > kHF - 1 ? kHF - 1 : Lr);
        i0r[r] = li0[Lr]; i1r[r] = li1[Lr]; awr[r] = lwt[Lr];
    }
    int F = min(i0r[0], min(i0r[1], i0r[2]));

    float wrow[3][3];  // [output row r][patch row pr]
#pragma unroll
    for (int r = 0; r < 3; r++) {
        int r0 = i0r[r] - F, r1 = i1r[r] - F;
#pragma unroll
        for (int pr = 0; pr < 3; pr++) {
            float wv = 0.0f;
            if (pr == r0) wv += 1.0f - awr[r];
            if (pr == r1) wv += awr[r];
            wrow[r][pr] = wv;
        }
    }

    // ---- longitude: output cols lon-1..lon+1 (periodic) -> patch cols ----
    float wcol[3][3];
    int G = 0;
    if (active) {
        int o0d[3], o1d[3];
        float owd[3];
#pragma unroll
        for (int d = 0; d < 3; d++) {
            int lm = (p_lon + d - 1 + kWF) % kWF;
            o0d[d] = oi0[lm]; o1d[d] = oi1[lm]; owd[d] = owt[lm];
        }
        G = o0d[0];
#pragma unroll
        for (int d = 0; d < 3; d++) {
            int c0 = (o0d[d] - G + kWP) % kWP;   // in {0,1}
            int c1 = (o1d[d] - G + kWP) % kWP;   // in {1,2}
#pragma unroll
            for (int pc = 0; pc < 3; pc++) {
                float wv = 0.0f;
                if (pc == c0) wv += 1.0f - owd[d];
                if (pc == c1) wv += owd[d];
                wcol[d][pc] = wv;
            }
        }
    }

    // ---- psi vals ----
    float vv[kK][kNB];
    if (active) {
#pragma unroll
        for (int k = 0; k < kK; k++) {
            const float* vp = dvals + ((size_t)k * kNPF + p) * kNB;
#pragma unroll
            for (int n = 0; n < kNB; n += 2) {
                float2 v2 = *(const float2*)(vp + n);
                vv[k][n] = v2.x; vv[k][n + 1] = v2.y;
            }
        }
    }

    // ---- collapse psi x bilinear into ck[k][3][3] ----
    const int RR[kNB] = {1, 1, 1, 2, 0, 2};
    const int CC[kNB] = {1, 2, 0, 1, 1, 2};
    float wb[kNB][3][3];
#pragma unroll
    for (int n = 0; n < kNB; n++)
#pragma unroll
        for (int pr = 0; pr < 3; pr++)
#pragma unroll
            for (int pc = 0; pc < 3; pc++)
                wb[n][pr][pc] = wrow[RR[n]][pr] * wcol[CC[n]][pc];

    float ck[kK][3][3];
#pragma unroll
    for (int k = 0; k < kK; k++)
#pragma unroll
        for (int pr = 0; pr < 3; pr++)
#pragma unroll
            for (int pc = 0; pc < 3; pc++) {
                float s = 0.0f;
#pragma unroll
                for (int n = 0; n < kNB; n++) s = fmaf(vv[k][n], wb[n][pr][pc], s);
                ck[k][pr][pc] = s;
            }

    // per-(pr,pc) column offsets (channel-independent parts)
    int colo[3];
#pragma unroll
    for (int pc = 0; pc < 3; pc++) colo[pc] = (G + pc) % kWP;

    float acc[kCOUT];
#pragma unroll
    for (int o = 0; o < kCOUT; o++) acc[o] = 0.0f;

    for (int c0 = 0; c0 < kCE; c0 += kCH) {
        __syncthreads();
        // phase A: stage kCH channels x 3 rows x 180 lon, writes linear in t
        for (int t = tid; t < kCH * 3 * kWP; t += 256) {
            int lon = t % kWP;
            int q   = t / kWP;
            int rr  = q % 3;
            int ii  = q / 3;
            int grow = F + rr; grow = grow > kHP - 1 ? kHP - 1 : grow;
            hs[t] = h[(size_t)(c0 + ii) * kNP + grow * kWP + lon];
        }
        __syncthreads();
        // phase B: stencil contraction
        if (active) {
#pragma unroll
            for (int ii = 0; ii < kCH; ii++) {
                float hv[3][3];
#pragma unroll
                for (int pr = 0; pr < 3; pr++) {
                    const float* hrow = &hs[(ii * 3 + pr) * kWP];
#pragma unroll
                    for (int pc = 0; pc < 3; pc++)
                        hv[pr][pc] = hrow[colo[pc]];
                }
                float z[kK];
#pragma unroll
                for (int k = 0; k < kK; k++) {
                    float s = 0.0f;
#pragma unroll
                    for (int pr = 0; pr < 3; pr++)
#pragma unroll
                        for (int pc = 0; pc < 3; pc++)
                            s = fmaf(ck[k][pr][pc], hv[pr][pc], s);
                    z[k] = s;
                }
                const float* wp = dwT + (size_t)(c0 + ii) * kCOUT * kK;
#pragma unroll
                for (int o = 0; o < kCOUT; o++) {
                    float s = acc[o];
#pragma unroll
                    for (int k = 0; k < kK; k++) s = fmaf(wp[o * kK + k], z[k], s);
                    acc[o] = s;
                }
            }
        }
    }

    if (active) {
#pragma unroll
        for (int o = 0; o < kCOUT; o++) out[(size_t)o * kNPF + p] = acc[o];
    }
}

// ---------------- host launcher ----------------
extern "C" void kernel_launch(void* const* d_in, const int* in_sizes, int n_in,
                              void* d_out, int out_size, void* d_ws, size_t ws_size,
                              hipStream_t stream) {
    const float* x         = (const float*)d_in[0];
    const int*   enc_idx   = (const int*)d_in[1];
    const float* enc_vals  = (const float*)d_in[2];
    const float* enc_w     = (const float*)d_in[3];
    const int*   proc_idx  = (const int*)d_in[4];
    const float* proc_vals = (const float*)d_in[5];
    const float* lw        = (const float*)d_in[6];
    const float* gw        = (const float*)d_in[7];
    const float* Pw        = (const float*)d_in[8];
    const float* Pi        = (const float*)d_in[9];
    const float* m1        = (const float*)d_in[10];
    const float* m2        = (const float*)d_in[11];
    const float* ls        = (const float*)d_in[12];
    const int*   li0       = (const int*)d_in[13];
    const int*   li1       = (const int*)d_in[14];
    const float* lwt       = (const float*)d_in[15];
    const int*   oi0       = (const int*)d_in[16];
    const int*   oi1       = (const int*)d_in[17];
    const float* owt       = (const float*)d_in[18];
    const int*   dec_idx   = (const int*)d_in[19];
    const float* dec_vals  = (const float*)d_in[20];
    const float* dec_w     = (const float*)d_in[21];
    float* out = (float*)d_out;
    (void)dec_idx;

    float* ws = (float*)d_ws;
    size_t off = 0;
    auto alloc = [&](size_t n) { float* p = ws + off; off += n; return p; };
    float* h    = alloc((size_t)kCE * kNP);
    float* xre  = alloc((size_t)kCE * kHP * kM);
    float* xim  = alloc((size_t)kCE * kHP * kM);
    float* cre  = alloc((size_t)kCE * kL * kM);
    float* cim  = alloc((size_t)kCE * kL * kM);
    float* c2re = alloc((size_t)kCE * kL * kM);
    float* c2im = alloc((size_t)kCE * kL * kM);
    float* dx   = alloc((size_t)kCE * kNP);
    float* dx1  = alloc((size_t)kHD * kNP);
    float* fc   = alloc((size_t)kM * kWP);
    float* fs   = alloc((size_t)kM * kWP);
    float* ic   = alloc((size_t)kM * kWP);
    float* isn  = alloc((size_t)kM * kWP);
    float* PwT  = alloc((size_t)kL * kM * kHP);
    float* PiT  = alloc((size_t)kL * kM * kHP);
    float* dwT  = alloc((size_t)kCOUT * kCE * kK);
    (void)ws_size; (void)in_sizes; (void)n_in; (void)out_size;

    dim3 B(256);
    auto nb = [](long long n) { return dim3((unsigned)((n + 255) / 256)); };

    k_prep1<<<nb(kM * kWP), B, 0, stream>>>(fc, fs, ic, isn, dec_w, dwT);
    k_prep2<<<nb(2LL * kL * kM * kHP), B, 0, stream>>>(Pw, Pi, PwT, PiT);

    // encoder
    k_disco<kCIN, kCE, 8><<<nb((long long)kNP * 8), B, 0, stream>>>(
        x, kNPF, enc_idx, enc_vals, enc_w, h, kNP);

    for (int i = 0; i < kNL; i++) {
        if (i % 2 == 0) {
            const float* gwl = gw + (size_t)(i / 2) * kCE * kCE * kL;
            k_rfft<<<nb((long long)kCE * kHP * kM), B, 0, stream>>>(h, fc, fs, xre, xim);
            k_sht<<<nb((long long)kCE * kL * kM), B, 0, stream>>>(PwT, xre, xim, cre, cim);
            k_gmix<<<nb((long long)kCE * kL * kM), B, 0, stream>>>(gwl, cre, cim, c2re, c2im);
            k_isht<<<nb((long long)kCE * kHP * kM), B, 0, stream>>>(PiT, c2re, c2im, xre, xim);
            k_irfft<<<nb((long long)kCE * kHP * kWP), B, 0, stream>>>(xre, xim, ic, isn, dx);
        } else {
            const float* lwl = lw + (size_t)(i / 2) * kCE * kCE * kK;
            k_disco<kCE, kCE, 8><<<nb((long long)kNP * 8), B, 0, stream>>>(
                h, kNP, proc_idx, proc_vals, lwl, dx, kNP);
        }
        k_mlp1<<<nb((long long)kHD * kNP), B, 0, stream>>>(m1 + (size_t)i * kHD * kCE, dx, dx1);
        k_mlp2<<<nb((long long)kCE * kNP), B, 0, stream>>>(m2 + (size_t)i * kCE * kHD, ls + (size_t)i * kCE, dx1, h);
    }

    // decoder: per-point 3x3 stencil, high occupancy
    k_dconv_s2<<<dim3(kHF * 3), B, 0, stream>>>(h, dec_vals, dwT,
                                                li0, li1, lwt, oi0, oi1, owt, out);
}

// Round 7
// 1058.292 us; speedup vs baseline: 1.3445x; 1.3445x over previous
//
#include <hip/hip_runtime.h>
#include <math.h>

// ---- problem constants ----
constexpr int kHF = 361, kWF = 720;       // full grid
constexpr int kHP = 90,  kWP = 180;       // processor grid
constexpr int kCIN = 26, kCE = 48, kCOUT = 24;
constexpr int kK = 9, kNB = 6;
constexpr int kL = 90, kM = 90;
constexpr int kNL = 4, kHD = 96;
constexpr int kNP  = kHP * kWP;           // 16200
constexpr int kNPF = kHF * kWF;           // 259920

#ifndef M_PI
#define M_PI 3.14159265358979323846
#endif

// ---------------- prep 1: DFT tables + decoder weight transpose ----------------
__global__ __launch_bounds__(256) void k_prep1(float* __restrict__ fc, float* __restrict__ fs,
                                               float* __restrict__ ic, float* __restrict__ isn,
                                               const float* __restrict__ dw, float* __restrict__ dwT) {
    int t = blockIdx.x * 256 + threadIdx.x;
    if (t < kM * kWP) {
        int m = t / kWP, w = t % kWP;
        double th = (2.0 * M_PI / (double)kWP) * (double)(m * w);
        double c = cos(th), s = sin(th);
        fc[w * kM + m] = (float)(c / (double)kWP);
        fs[w * kM + m] = (float)(-s / (double)kWP);
        float sc = (m == 0) ? 1.0f : 2.0f;
        ic[m * kWP + w] = sc * (float)c;
        isn[m * kWP + w] = sc * (float)s;
    }
    if (t < kCOUT * kCE * kK) {
        int k = t % kK;
        int i = (t / kK) % kCE;
        int o = t / (kK * kCE);
        dwT[((size_t)i * kCOUT + o) * kK + k] = dw[t];
    }
}

// ---------------- prep 2: transpose both Legendre matrices ----------------
__global__ __launch_bounds__(256) void k_prep2(const float* __restrict__ Pw, const float* __restrict__ Pi,
                                               float* __restrict__ PwT, float* __restrict__ PiT) {
    int t = blockIdx.x * 256 + threadIdx.x;
    int N = kL * kM * kHP;
    if (t >= 2 * N) return;
    int mode = t >= N ? 1 : 0;
    int u = mode ? t - N : t;
    int l = u / (kM * kHP);
    int r = u % (kM * kHP);
    int m = r / kHP;
    int tt = r % kHP;
    if (mode == 0) PwT[(l * kHP + tt) * kM + m] = Pw[u];
    else           PiT[(tt * kL + l) * kM + m] = Pi[u];
}

// ---------------- disco conv (encoder / processor) ----------------
template <int TCIN, int TCOUT, int OG>
__global__ __launch_bounds__(256) void k_disco(const float* __restrict__ src, int srcStride,
                                               const int* __restrict__ idx, const float* __restrict__ vals,
                                               const float* __restrict__ w, float* __restrict__ out, int np) {
    int gt = blockIdx.x * 256 + threadIdx.x;
    if (gt >= np * OG) return;
    int p = gt % np;
    int og = gt / np;
    constexpr int OC = TCOUT / OG;

    int qi[kNB];
#pragma unroll
    for (int n = 0; n < kNB; n++) qi[n] = idx[p * kNB + n];

    float vv[kK][kNB];
#pragma unroll
    for (int k = 0; k < kK; k++) {
        const float* vp = vals + ((size_t)k * np + p) * kNB;
#pragma unroll
        for (int n = 0; n < kNB; n += 2) {
            float2 v2 = *(const float2*)(vp + n);
            vv[k][n] = v2.x; vv[k][n + 1] = v2.y;
        }
    }

    float acc[OC];
#pragma unroll
    for (int o = 0; o < OC; o++) acc[o] = 0.0f;

    const float* wbase = w + (size_t)og * OC * TCIN * kK;

    for (int i = 0; i < TCIN; i++) {
        float xg[kNB];
#pragma unroll
        for (int n = 0; n < kNB; n++) xg[n] = src[i * srcStride + qi[n]];
        float z[kK];
#pragma unroll
        for (int k = 0; k < kK; k++) {
            float zz = 0.0f;
#pragma unroll
            for (int n = 0; n < kNB; n++) zz = fmaf(vv[k][n], xg[n], zz);
            z[k] = zz;
        }
#pragma unroll
        for (int o = 0; o < OC; o++) {
            const float* wp = wbase + ((size_t)o * TCIN + i) * kK;
            float s = acc[o];
#pragma unroll
            for (int k = 0; k < kK; k++) s = fmaf(wp[k], z[k], s);
            acc[o] = s;
        }
    }
#pragma unroll
    for (int o = 0; o < OC; o++) out[(size_t)(og * OC + o) * np + p] = acc[o];
}

// ---------------- spectral pipeline ----------------
__global__ __launch_bounds__(256) void k_rfft(const float* __restrict__ g, const float* __restrict__ fc,
                                              const float* __restrict__ fs, float* __restrict__ xre,
                                              float* __restrict__ xim) {
    int t = blockIdx.x * 256 + threadIdx.x;
    if (t >= kCE * kHP * kM) return;
    int m = t % kM;
    int row = t / kM;
    const float* gr = g + (size_t)row * kWP;
    float ar = 0.0f, ai = 0.0f;
    for (int w = 0; w < kWP; w++) {
        float gv = gr[w];
        ar = fmaf(gv, fc[w * kM + m], ar);
        ai = fmaf(gv, fs[w * kM + m], ai);
    }
    xre[t] = ar;
    xim[t] = ai;
}

__global__ __launch_bounds__(256) void k_sht(const float* __restrict__ PwT, const float* __restrict__ xre,
                                             const float* __restrict__ xim, float* __restrict__ cre,
                                             float* __restrict__ cim) {
    int t = blockIdx.x * 256 + threadIdx.x;
    if (t >= kCE * kL * kM) return;
    int m = t % kM;
    int l = (t / kM) % kL;
    int c = t / (kM * kL);
    float ar = 0.0f, ai = 0.0f;
    for (int tt = 0; tt < kHP; tt++) {
        float pv = PwT[((size_t)l * kHP + tt) * kM + m];
        ar = fmaf(pv, xre[((size_t)c * kHP + tt) * kM + m], ar);
        ai = fmaf(pv, xim[((size_t)c * kHP + tt) * kM + m], ai);
    }
    cre[t] = ar;
    cim[t] = ai;
}

__global__ __launch_bounds__(256) void k_gmix(const float* __restrict__ gwl, const float* __restrict__ cre,
                                              const float* __restrict__ cim, float* __restrict__ ore,
                                              float* __restrict__ oim) {
    int t = blockIdx.x * 256 + threadIdx.x;
    if (t >= kCE * kL * kM) return;
    int m = t % kM;
    int l = (t / kM) % kL;
    int o = t / (kM * kL);
    float ar = 0.0f, ai = 0.0f;
    for (int i = 0; i < kCE; i++) {
        float gv = gwl[((size_t)o * kCE + i) * kL + l];
        ar = fmaf(gv, cre[((size_t)i * kL + l) * kM + m], ar);
        ai = fmaf(gv, cim[((size_t)i * kL + l) * kM + m], ai);
    }
    ore[t] = ar;
    oim[t] = ai;
}

__global__ __launch_bounds__(256) void k_isht(const float* __restrict__ PiT, const float* __restrict__ cre,
                                              const float* __restrict__ cim, float* __restrict__ xre,
                                              float* __restrict__ xim) {
    int t = blockIdx.x * 256 + threadIdx.x;
    if (t >= kCE * kHP * kM) return;
    int m = t % kM;
    int tt = (t / kM) % kHP;
    int c = t / (kM * kHP);
    float ar = 0.0f, ai = 0.0f;
    for (int l = 0; l < kL; l++) {
        float pv = PiT[((size_t)tt * kL + l) * kM + m];
        ar = fmaf(pv, cre[((size_t)c * kL + l) * kM + m], ar);
        ai = fmaf(pv, cim[((size_t)c * kL + l) * kM + m], ai);
    }
    xre[t] = ar;
    xim[t] = ai;
}

__global__ __launch_bounds__(256) void k_irfft(const float* __restrict__ xre, const float* __restrict__ xim,
                                               const float* __restrict__ ic, const float* __restrict__ isn,
                                               float* __restrict__ dx) {
    int t = blockIdx.x * 256 + threadIdx.x;
    if (t >= kCE * kHP * kWP) return;
    int w = t % kWP;
    int row = t / kWP;
    const float* xr = xre + (size_t)row * kM;
    const float* xi = xim + (size_t)row * kM;
    float a = 0.0f;
    for (int m = 0; m < kM; m++) {
        a = fmaf(xr[m], ic[m * kWP + w], a);
        a = fmaf(-xi[m], isn[m * kWP + w], a);
    }
    dx[t] = a;
}

// ---------------- MLP (split, highly parallel) ----------------
__device__ __forceinline__ float gelu_tanh(float x) {
    float x3 = x * x * x;
    float t = tanhf(0.7978845608028654f * (x + 0.044715f * x3));
    return 0.5f * x * (1.0f + t);
}

__global__ __launch_bounds__(256) void k_mlp1(const float* __restrict__ m1w, const float* __restrict__ dx,
                                              float* __restrict__ dx1) {
    int t = blockIdx.x * 256 + threadIdx.x;
    if (t >= kHD * kNP) return;
    int p = t % kNP;
    int hh = t / kNP;
    float a = 0.0f;
    for (int i = 0; i < kCE; i++) a = fmaf(m1w[hh * kCE + i], dx[(size_t)i * kNP + p], a);
    dx1[t] = gelu_tanh(a);
}

__global__ __launch_bounds__(256) void k_mlp2(const float* __restrict__ m2w, const float* __restrict__ lsw,
                                              const float* __restrict__ dx1, float* __restrict__ h) {
    int t = blockIdx.x * 256 + threadIdx.x;
    if (t >= kCE * kNP) return;
    int p = t % kNP;
    int o = t / kNP;
    float a = 0.0f;
    for (int j = 0; j < kHD; j++) a = fmaf(m2w[o * kHD + j], dx1[(size_t)j * kNP + p], a);
    h[t] = h[t] + lsw[o] * a;
}

// ---------------- decoder: per-point 3x3 stencil, flat LDS, natural VGPR ----------------
// out[o,p] is linear in h over a 3-row x 3-col patch (rows F..F+2, cols G..G+2 mod 180).
// Per thread: ck[9][3][3] built once; per channel: 9 LDS reads + 81 + 216 FMA.
// LDS layout hs[(ii*3+rr)*180 + lon]: staging writes linear in t (conflict-free);
// reads are 16-consecutive-word groups with 4-lane broadcast (conflict-free).
// NOTE: no min-waves clause — (256,4) capped VGPR at 64 and caused 500 MB of
// scratch spill traffic (round 6). Natural allocation is ~92 VGPR, no spill.
constexpr int kT   = 240;   // outputs per block
constexpr int kCH  = 8;     // channel chunk

__global__ __launch_bounds__(256) void k_dconv_s3(const float* __restrict__ h,
                                                  const float* __restrict__ dvals,
                                                  const float* __restrict__ dwT,
                                                  const int* __restrict__ li0, const int* __restrict__ li1,
                                                  const float* __restrict__ lwt, const int* __restrict__ oi0,
                                                  const int* __restrict__ oi1, const float* __restrict__ owt,
                                                  float* __restrict__ out) {
    __shared__ float hs[kCH * 3 * kWP];  // 4320 floats = 17.3 KB

    int blk = blockIdx.x;
    int lat = blk / 3;
    int seg = blk % 3;
    int lon0 = seg * kT;
    int tid = threadIdx.x;
    bool active = tid < kT;
    int p_lon = lon0 + tid;
    int p = lat * kWF + p_lon;

    // ---- latitude: output rows lat-1..lat+1 (clipped) -> patch rows ----
    int i0r[3], i1r[3];
    float awr[3];
#pragma unroll
    for (int r = 0; r < 3; r++) {
        int Lr = lat - 1 + r;
        Lr = Lr < 0 ? 0 : (Lr > kHF - 1 ? kHF - 1 : Lr);
        i0r[r] = li0[Lr]; i1r[r] = li1[Lr]; awr[r] = lwt[Lr];
    }
    int F = min(i0r[0], min(i0r[1], i0r[2]));

    float wrow[3][3];  // [output row r][patch row pr]
#pragma unroll
    for (int r = 0; r < 3; r++) {
        int r0 = i0r[r] - F, r1 = i1r[r] - F;
#pragma unroll
        for (int pr = 0; pr < 3; pr++) {
            float wv = 0.0f;
            if (pr == r0) wv += 1.0f - awr[r];
            if (pr == r1) wv += awr[r];
            wrow[r][pr] = wv;
        }
    }

    // ---- longitude: output cols lon-1..lon+1 (periodic) -> patch cols ----
    float wcol[3][3];
    int G = 0;
    if (active) {
        int o0d[3], o1d[3];
        float owd[3];
#pragma unroll
        for (int d = 0; d < 3; d++) {
            int lm = (p_lon + d - 1 + kWF) % kWF;
            o0d[d] = oi0[lm]; o1d[d] = oi1[lm]; owd[d] = owt[lm];
        }
        G = o0d[0];
#pragma unroll
        for (int d = 0; d < 3; d++) {
            int c0 = (o0d[d] - G + kWP) % kWP;   // in {0,1}
            int c1 = (o1d[d] - G + kWP) % kWP;   // in {1,2}
#pragma unroll
            for (int pc = 0; pc < 3; pc++) {
                float wv = 0.0f;
                if (pc == c0) wv += 1.0f - owd[d];
                if (pc == c1) wv += owd[d];
                wcol[d][pc] = wv;
            }
        }
    }

    // ---- psi vals ----
    float vv[kK][kNB];
    if (active) {
#pragma unroll
        for (int k = 0; k < kK; k++) {
            const float* vp = dvals + ((size_t)k * kNPF + p) * kNB;
#pragma unroll
            for (int n = 0; n < kNB; n += 2) {
                float2 v2 = *(const float2*)(vp + n);
                vv[k][n] = v2.x; vv[k][n + 1] = v2.y;
            }
        }
    }

    // ---- collapse psi x bilinear into ck[k][3][3] ----
    const int RR[kNB] = {1, 1, 1, 2, 0, 2};
    const int CC[kNB] = {1, 2, 0, 1, 1, 2};
    float wb[kNB][3][3];
#pragma unroll
    for (int n = 0; n < kNB; n++)
#pragma unroll
        for (int pr = 0; pr < 3; pr++)
#pragma unroll
            for (int pc = 0; pc < 3; pc++)
                wb[n][pr][pc] = wrow[RR[n]][pr] * wcol[CC[n]][pc];

    float ck[kK][3][3];
#pragma unroll
    for (int k = 0; k < kK; k++)
#pragma unroll
        for (int pr = 0; pr < 3; pr++)
#pragma unroll
            for (int pc = 0; pc < 3; pc++) {
                float s = 0.0f;
#pragma unroll
                for (int n = 0; n < kNB; n++) s = fmaf(vv[k][n], wb[n][pr][pc], s);
                ck[k][pr][pc] = s;
            }

    // per-column LDS offsets (channel-independent)
    int colo[3];
#pragma unroll
    for (int pc = 0; pc < 3; pc++) colo[pc] = (G + pc) % kWP;

    float acc[kCOUT];
#pragma unroll
    for (int o = 0; o < kCOUT; o++) acc[o] = 0.0f;

    for (int c0 = 0; c0 < kCE; c0 += kCH) {
        __syncthreads();
        // phase A: stage kCH channels x 3 rows x 180 lon, writes linear in t
        for (int t = tid; t < kCH * 3 * kWP; t += 256) {
            int lon = t % kWP;
            int q   = t / kWP;
            int rr  = q % 3;
            int ii  = q / 3;
            int grow = F + rr; grow = grow > kHP - 1 ? kHP - 1 : grow;
            hs[t] = h[(size_t)(c0 + ii) * kNP + grow * kWP + lon];
        }
        __syncthreads();
        // phase B: stencil contraction
        if (active) {
#pragma unroll
            for (int ii = 0; ii < kCH; ii++) {
                float hv[3][3];
#pragma unroll
                for (int pr = 0; pr < 3; pr++) {
                    const float* hrow = &hs[(ii * 3 + pr) * kWP];
#pragma unroll
                    for (int pc = 0; pc < 3; pc++)
                        hv[pr][pc] = hrow[colo[pc]];
                }
                float z[kK];
#pragma unroll
                for (int k = 0; k < kK; k++) {
                    float s = 0.0f;
#pragma unroll
                    for (int pr = 0; pr < 3; pr++)
#pragma unroll
                        for (int pc = 0; pc < 3; pc++)
                            s = fmaf(ck[k][pr][pc], hv[pr][pc], s);
                    z[k] = s;
                }
                const float* wp = dwT + (size_t)(c0 + ii) * kCOUT * kK;
#pragma unroll
                for (int o = 0; o < kCOUT; o++) {
                    float s = acc[o];
#pragma unroll
                    for (int k = 0; k < kK; k++) s = fmaf(wp[o * kK + k], z[k], s);
                    acc[o] = s;
                }
            }
        }
    }

    if (active) {
#pragma unroll
        for (int o = 0; o < kCOUT; o++) out[(size_t)o * kNPF + p] = acc[o];
    }
}

// ---------------- host launcher ----------------
extern "C" void kernel_launch(void* const* d_in, const int* in_sizes, int n_in,
                              void* d_out, int out_size, void* d_ws, size_t ws_size,
                              hipStream_t stream) {
    const float* x         = (const float*)d_in[0];
    const int*   enc_idx   = (const int*)d_in[1];
    const float* enc_vals  = (const float*)d_in[2];
    const float* enc_w     = (const float*)d_in[3];
    const int*   proc_idx  = (const int*)d_in[4];
    const float* proc_vals = (const float*)d_in[5];
    const float* lw        = (const float*)d_in[6];
    const float* gw        = (const float*)d_in[7];
    const float* Pw        = (const float*)d_in[8];
    const float* Pi        = (const float*)d_in[9];
    const float* m1        = (const float*)d_in[10];
    const float* m2        = (const float*)d_in[11];
    const float* ls        = (const float*)d_in[12];
    const int*   li0       = (const int*)d_in[13];
    const int*   li1       = (const int*)d_in[14];
    const float* lwt       = (const float*)d_in[15];
    const int*   oi0       = (const int*)d_in[16];
    const int*   oi1       = (const int*)d_in[17];
    const float* owt       = (const float*)d_in[18];
    const int*   dec_idx   = (const int*)d_in[19];
    const float* dec_vals  = (const float*)d_in[20];
    const float* dec_w     = (const float*)d_in[21];
    float* out = (float*)d_out;
    (void)dec_idx;

    float* ws = (float*)d_ws;
    size_t off = 0;
    auto alloc = [&](size_t n) { float* p = ws + off; off += n; return p; };
    float* h    = alloc((size_t)kCE * kNP);
    float* xre  = alloc((size_t)kCE * kHP * kM);
    float* xim  = alloc((size_t)kCE * kHP * kM);
    float* cre  = alloc((size_t)kCE * kL * kM);
    float* cim  = alloc((size_t)kCE * kL * kM);
    float* c2re = alloc((size_t)kCE * kL * kM);
    float* c2im = alloc((size_t)kCE * kL * kM);
    float* dx   = alloc((size_t)kCE * kNP);
    float* dx1  = alloc((size_t)kHD * kNP);
    float* fc   = alloc((size_t)kM * kWP);
    float* fs   = alloc((size_t)kM * kWP);
    float* ic   = alloc((size_t)kM * kWP);
    float* isn  = alloc((size_t)kM * kWP);
    float* PwT  = alloc((size_t)kL * kM * kHP);
    float* PiT  = alloc((size_t)kL * kM * kHP);
    float* dwT  = alloc((size_t)kCOUT * kCE * kK);
    (void)ws_size; (void)in_sizes; (void)n_in; (void)out_size;

    dim3 B(256);
    auto nb = [](long long n) { return dim3((unsigned)((n + 255) / 256)); };

    k_prep1<<<nb(kM * kWP), B, 0, stream>>>(fc, fs, ic, isn, dec_w, dwT);
    k_prep2<<<nb(2LL * kL * kM * kHP), B, 0, stream>>>(Pw, Pi, PwT, PiT);

    // encoder
    k_disco<kCIN, kCE, 8><<<nb((long long)kNP * 8), B, 0, stream>>>(
        x, kNPF, enc_idx, enc_vals, enc_w, h, kNP);

    for (int i = 0; i < kNL; i++) {
        if (i % 2 == 0) {
            const float* gwl = gw + (size_t)(i / 2) * kCE * kCE * kL;
            k_rfft<<<nb((long long)kCE * kHP * kM), B, 0, stream>>>(h, fc, fs, xre, xim);
            k_sht<<<nb((long long)kCE * kL * kM), B, 0, stream>>>(PwT, xre, xim, cre, cim);
            k_gmix<<<nb((long long)kCE * kL * kM), B, 0, stream>>>(gwl, cre, cim, c2re, c2im);
            k_isht<<<nb((long long)kCE * kHP * kM), B, 0, stream>>>(PiT, c2re, c2im, xre, xim);
            k_irfft<<<nb((long long)kCE * kHP * kWP), B, 0, stream>>>(xre, xim, ic, isn, dx);
        } else {
            const float* lwl = lw + (size_t)(i / 2) * kCE * kCE * kK;
            k_disco<kCE, kCE, 8><<<nb((long long)kNP * 8), B, 0, stream>>>(
                h, kNP, proc_idx, proc_vals, lwl, dx, kNP);
        }
        k_mlp1<<<nb((long long)kHD * kNP), B, 0, stream>>>(m1 + (size_t)i * kHD * kCE, dx, dx1);
        k_mlp2<<<nb((long long)kCE * kNP), B, 0, stream>>>(m2 + (size_t)i * kCE * kHD, ls + (size_t)i * kCE, dx1, h);
    }

    // decoder: per-point 3x3 stencil, flat LDS, natural VGPR
    k_dconv_s3<<<dim3(kHF * 3), B, 0, stream>>>(h, dec_vals, dwT,
                                                li0, li1, lwt, oi0, oi1, owt, out);
}

// Round 8
// 854.653 us; speedup vs baseline: 1.6649x; 1.2383x over previous
//
#include <hip/hip_runtime.h>
#include <math.h>

// ---- problem constants ----
constexpr int kHF = 361, kWF = 720;       // full grid
constexpr int kHP = 90,  kWP = 180;       // processor grid
constexpr int kCIN = 26, kCE = 48, kCOUT = 24;
constexpr int kK = 9, kNB = 6;
constexpr int kL = 90, kM = 90;
constexpr int kNL = 4, kHD = 96;
constexpr int kNP  = kHP * kWP;           // 16200
constexpr int kNPF = kHF * kWF;           // 259920

#ifndef M_PI
#define M_PI 3.14159265358979323846
#endif

// ---------------- prep 1: DFT tables + decoder weight transpose ----------------
__global__ __launch_bounds__(256) void k_prep1(float* __restrict__ fc, float* __restrict__ fs,
                                               float* __restrict__ ic, float* __restrict__ isn,
                                               const float* __restrict__ dw, float* __restrict__ dwT) {
    int t = blockIdx.x * 256 + threadIdx.x;
    if (t < kM * kWP) {
        int m = t / kWP, w = t % kWP;
        double th = (2.0 * M_PI / (double)kWP) * (double)(m * w);
        double c = cos(th), s = sin(th);
        fc[w * kM + m] = (float)(c / (double)kWP);
        fs[w * kM + m] = (float)(-s / (double)kWP);
        float sc = (m == 0) ? 1.0f : 2.0f;
        ic[m * kWP + w] = sc * (float)c;
        isn[m * kWP + w] = sc * (float)s;
    }
    if (t < kCOUT * kCE * kK) {
        int k = t % kK;
        int i = (t / kK) % kCE;
        int o = t / (kK * kCE);
        dwT[((size_t)i * kCOUT + o) * kK + k] = dw[t];
    }
}

// ---------------- prep 2: transpose both Legendre matrices ----------------
__global__ __launch_bounds__(256) void k_prep2(const float* __restrict__ Pw, const float* __restrict__ Pi,
                                               float* __restrict__ PwT, float* __restrict__ PiT) {
    int t = blockIdx.x * 256 + threadIdx.x;
    int N = kL * kM * kHP;
    if (t >= 2 * N) return;
    int mode = t >= N ? 1 : 0;
    int u = mode ? t - N : t;
    int l = u / (kM * kHP);
    int r = u % (kM * kHP);
    int m = r / kHP;
    int tt = r % kHP;
    if (mode == 0) PwT[(l * kHP + tt) * kM + m] = Pw[u];
    else           PiT[(tt * kL + l) * kM + m] = Pi[u];
}

// ---------------- disco conv (encoder / processor) ----------------
template <int TCIN, int TCOUT, int OG>
__global__ __launch_bounds__(256) void k_disco(const float* __restrict__ src, int srcStride,
                                               const int* __restrict__ idx, const float* __restrict__ vals,
                                               const float* __restrict__ w, float* __restrict__ out, int np) {
    int gt = blockIdx.x * 256 + threadIdx.x;
    if (gt >= np * OG) return;
    int p = gt % np;
    int og = gt / np;
    constexpr int OC = TCOUT / OG;

    int qi[kNB];
#pragma unroll
    for (int n = 0; n < kNB; n++) qi[n] = idx[p * kNB + n];

    float vv[kK][kNB];
#pragma unroll
    for (int k = 0; k < kK; k++) {
        const float* vp = vals + ((size_t)k * np + p) * kNB;
#pragma unroll
        for (int n = 0; n < kNB; n += 2) {
            float2 v2 = *(const float2*)(vp + n);
            vv[k][n] = v2.x; vv[k][n + 1] = v2.y;
        }
    }

    float acc[OC];
#pragma unroll
    for (int o = 0; o < OC; o++) acc[o] = 0.0f;

    const float* wbase = w + (size_t)og * OC * TCIN * kK;

    for (int i = 0; i < TCIN; i++) {
        float xg[kNB];
#pragma unroll
        for (int n = 0; n < kNB; n++) xg[n] = src[i * srcStride + qi[n]];
        float z[kK];
#pragma unroll
        for (int k = 0; k < kK; k++) {
            float zz = 0.0f;
#pragma unroll
            for (int n = 0; n < kNB; n++) zz = fmaf(vv[k][n], xg[n], zz);
            z[k] = zz;
        }
#pragma unroll
        for (int o = 0; o < OC; o++) {
            const float* wp = wbase + ((size_t)o * TCIN + i) * kK;
            float s = acc[o];
#pragma unroll
            for (int k = 0; k < kK; k++) s = fmaf(wp[k], z[k], s);
            acc[o] = s;
        }
    }
#pragma unroll
    for (int o = 0; o < OC; o++) out[(size_t)(og * OC + o) * np + p] = acc[o];
}

// ---------------- spectral pipeline ----------------
__global__ __launch_bounds__(256) void k_rfft(const float* __restrict__ g, const float* __restrict__ fc,
                                              const float* __restrict__ fs, float* __restrict__ xre,
                                              float* __restrict__ xim) {
    int t = blockIdx.x * 256 + threadIdx.x;
    if (t >= kCE * kHP * kM) return;
    int m = t % kM;
    int row = t / kM;
    const float* gr = g + (size_t)row * kWP;
    float ar = 0.0f, ai = 0.0f;
    for (int w = 0; w < kWP; w++) {
        float gv = gr[w];
        ar = fmaf(gv, fc[w * kM + m], ar);
        ai = fmaf(gv, fs[w * kM + m], ai);
    }
    xre[t] = ar;
    xim[t] = ai;
}

__global__ __launch_bounds__(256) void k_sht(const float* __restrict__ PwT, const float* __restrict__ xre,
                                             const float* __restrict__ xim, float* __restrict__ cre,
                                             float* __restrict__ cim) {
    int t = blockIdx.x * 256 + threadIdx.x;
    if (t >= kCE * kL * kM) return;
    int m = t % kM;
    int l = (t / kM) % kL;
    int c = t / (kM * kL);
    float ar = 0.0f, ai = 0.0f;
    for (int tt = 0; tt < kHP; tt++) {
        float pv = PwT[((size_t)l * kHP + tt) * kM + m];
        ar = fmaf(pv, xre[((size_t)c * kHP + tt) * kM + m], ar);
        ai = fmaf(pv, xim[((size_t)c * kHP + tt) * kM + m], ai);
    }
    cre[t] = ar;
    cim[t] = ai;
}

__global__ __launch_bounds__(256) void k_gmix(const float* __restrict__ gwl, const float* __restrict__ cre,
                                              const float* __restrict__ cim, float* __restrict__ ore,
                                              float* __restrict__ oim) {
    int t = blockIdx.x * 256 + threadIdx.x;
    if (t >= kCE * kL * kM) return;
    int m = t % kM;
    int l = (t / kM) % kL;
    int o = t / (kM * kL);
    float ar = 0.0f, ai = 0.0f;
    for (int i = 0; i < kCE; i++) {
        float gv = gwl[((size_t)o * kCE + i) * kL + l];
        ar = fmaf(gv, cre[((size_t)i * kL + l) * kM + m], ar);
        ai = fmaf(gv, cim[((size_t)i * kL + l) * kM + m], ai);
    }
    ore[t] = ar;
    oim[t] = ai;
}

__global__ __launch_bounds__(256) void k_isht(const float* __restrict__ PiT, const float* __restrict__ cre,
                                              const float* __restrict__ cim, float* __restrict__ xre,
                                              float* __restrict__ xim) {
    int t = blockIdx.x * 256 + threadIdx.x;
    if (t >= kCE * kHP * kM) return;
    int m = t % kM;
    int tt = (t / kM) % kHP;
    int c = t / (kM * kHP);
    float ar = 0.0f, ai = 0.0f;
    for (int l = 0; l < kL; l++) {
        float pv = PiT[((size_t)tt * kL + l) * kM + m];
        ar = fmaf(pv, cre[((size_t)c * kL + l) * kM + m], ar);
        ai = fmaf(pv, cim[((size_t)c * kL + l) * kM + m], ai);
    }
    xre[t] = ar;
    xim[t] = ai;
}

__global__ __launch_bounds__(256) void k_irfft(const float* __restrict__ xre, const float* __restrict__ xim,
                                               const float* __restrict__ ic, const float* __restrict__ isn,
                                               float* __restrict__ dx) {
    int t = blockIdx.x * 256 + threadIdx.x;
    if (t >= kCE * kHP * kWP) return;
    int w = t % kWP;
    int row = t / kWP;
    const float* xr = xre + (size_t)row * kM;
    const float* xi = xim + (size_t)row * kM;
    float a = 0.0f;
    for (int m = 0; m < kM; m++) {
        a = fmaf(xr[m], ic[m * kWP + w], a);
        a = fmaf(-xi[m], isn[m * kWP + w], a);
    }
    dx[t] = a;
}

// ---------------- MLP (split, highly parallel) ----------------
__device__ __forceinline__ float gelu_tanh(float x) {
    float x3 = x * x * x;
    float t = tanhf(0.7978845608028654f * (x + 0.044715f * x3));
    return 0.5f * x * (1.0f + t);
}

__global__ __launch_bounds__(256) void k_mlp1(const float* __restrict__ m1w, const float* __restrict__ dx,
                                              float* __restrict__ dx1) {
    int t = blockIdx.x * 256 + threadIdx.x;
    if (t >= kHD * kNP) return;
    int p = t % kNP;
    int hh = t / kNP;
    float a = 0.0f;
    for (int i = 0; i < kCE; i++) a = fmaf(m1w[hh * kCE + i], dx[(size_t)i * kNP + p], a);
    dx1[t] = gelu_tanh(a);
}

__global__ __launch_bounds__(256) void k_mlp2(const float* __restrict__ m2w, const float* __restrict__ lsw,
                                              const float* __restrict__ dx1, float* __restrict__ h) {
    int t = blockIdx.x * 256 + threadIdx.x;
    if (t >= kCE * kNP) return;
    int p = t % kNP;
    int o = t / kNP;
    float a = 0.0f;
    for (int j = 0; j < kHD; j++) a = fmaf(m2w[o * kHD + j], dx1[(size_t)j * kNP + p], a);
    h[t] = h[t] + lsw[o] * a;
}

// ---------------- decoder: per-point 3x3 stencil, DIRECT from global (no LDS) ----------------
// h (3.1 MB) is fully L2-resident; the 9 patch loads per channel are coalesced
// by construction (consecutive threads = consecutive lon = consecutive addresses).
// L2 traffic 450 MB @ ~34 TB/s ≈ 13 µs — bandwidth is free. No barriers, no LDS:
// waves run independently, compiler pipelines the 9 loads against the 297 FMAs.
// Weight reads (dwT) are wave-uniform -> scalar pipe.
__global__ __launch_bounds__(256) void k_dconv_d(const float* __restrict__ h,
                                                 const float* __restrict__ dvals,
                                                 const float* __restrict__ dwT,
                                                 const int* __restrict__ li0, const int* __restrict__ li1,
                                                 const float* __restrict__ lwt, const int* __restrict__ oi0,
                                                 const int* __restrict__ oi1, const float* __restrict__ owt,
                                                 float* __restrict__ out) {
    int p = blockIdx.x * 256 + threadIdx.x;
    if (p >= kNPF) return;
    int lat = p / kWF;
    int p_lon = p - lat * kWF;

    // ---- latitude: output rows lat-1..lat+1 (clipped) -> patch rows F..F+2 ----
    int i0r[3], i1r[3];
    float awr[3];
#pragma unroll
    for (int r = 0; r < 3; r++) {
        int Lr = lat - 1 + r;
        Lr = Lr < 0 ? 0 : (Lr > kHF - 1 ? kHF - 1 : Lr);
        i0r[r] = li0[Lr]; i1r[r] = li1[Lr]; awr[r] = lwt[Lr];
    }
    int F = min(i0r[0], min(i0r[1], i0r[2]));

    float wrow[3][3];  // [output row r][patch row pr]
#pragma unroll
    for (int r = 0; r < 3; r++) {
        int r0 = i0r[r] - F, r1 = i1r[r] - F;
#pragma unroll
        for (int pr = 0; pr < 3; pr++) {
            float wv = 0.0f;
            if (pr == r0) wv += 1.0f - awr[r];
            if (pr == r1) wv += awr[r];
            wrow[r][pr] = wv;
        }
    }

    // ---- longitude: output cols lon-1..lon+1 (periodic) -> patch cols G..G+2 ----
    int o0d[3], o1d[3];
    float owd[3];
#pragma unroll
    for (int d = 0; d < 3; d++) {
        int lm = (p_lon + d - 1 + kWF) % kWF;
        o0d[d] = oi0[lm]; o1d[d] = oi1[lm]; owd[d] = owt[lm];
    }
    int G = o0d[0];
    float wcol[3][3];
#pragma unroll
    for (int d = 0; d < 3; d++) {
        int c0 = (o0d[d] - G + kWP) % kWP;   // in {0,1}
        int c1 = (o1d[d] - G + kWP) % kWP;   // in {1,2}
#pragma unroll
        for (int pc = 0; pc < 3; pc++) {
            float wv = 0.0f;
            if (pc == c0) wv += 1.0f - owd[d];
            if (pc == c1) wv += owd[d];
            wcol[d][pc] = wv;
        }
    }

    // ---- psi vals ----
    float vv[kK][kNB];
#pragma unroll
    for (int k = 0; k < kK; k++) {
        const float* vp = dvals + ((size_t)k * kNPF + p) * kNB;
#pragma unroll
        for (int n = 0; n < kNB; n += 2) {
            float2 v2 = *(const float2*)(vp + n);
            vv[k][n] = v2.x; vv[k][n + 1] = v2.y;
        }
    }

    // ---- collapse psi x bilinear into ck[k][3][3] ----
    const int RR[kNB] = {1, 1, 1, 2, 0, 2};
    const int CC[kNB] = {1, 2, 0, 1, 1, 2};
    float ck[kK][3][3];
#pragma unroll
    for (int k = 0; k < kK; k++)
#pragma unroll
        for (int pr = 0; pr < 3; pr++)
#pragma unroll
            for (int pc = 0; pc < 3; pc++) {
                float s = 0.0f;
#pragma unroll
                for (int n = 0; n < kNB; n++)
                    s = fmaf(vv[k][n], wrow[RR[n]][pr] * wcol[CC[n]][pc], s);
                ck[k][pr][pc] = s;
            }

    // ---- 9 patch element offsets into h (channel 0); step kNP per channel ----
    int ofs[3][3];
#pragma unroll
    for (int pr = 0; pr < 3; pr++) {
        int row = F + pr; row = row > kHP - 1 ? kHP - 1 : row;
#pragma unroll
        for (int pc = 0; pc < 3; pc++) {
            int col = (G + pc) % kWP;
            ofs[pr][pc] = row * kWP + col;
        }
    }

    float acc[kCOUT];
#pragma unroll
    for (int o = 0; o < kCOUT; o++) acc[o] = 0.0f;

    const float* wp = dwT;  // advances kCOUT*kK per channel
    const float* hi = h;    // advances kNP per channel
#pragma unroll 2
    for (int i = 0; i < kCE; i++) {
        float hv[3][3];
#pragma unroll
        for (int pr = 0; pr < 3; pr++)
#pragma unroll
            for (int pc = 0; pc < 3; pc++)
                hv[pr][pc] = hi[ofs[pr][pc]];
        float z[kK];
#pragma unroll
        for (int k = 0; k < kK; k++) {
            float s = 0.0f;
#pragma unroll
            for (int pr = 0; pr < 3; pr++)
#pragma unroll
                for (int pc = 0; pc < 3; pc++)
                    s = fmaf(ck[k][pr][pc], hv[pr][pc], s);
            z[k] = s;
        }
#pragma unroll
        for (int o = 0; o < kCOUT; o++) {
            float s = acc[o];
#pragma unroll
            for (int k = 0; k < kK; k++) s = fmaf(wp[o * kK + k], z[k], s);
            acc[o] = s;
        }
        wp += kCOUT * kK;
        hi += kNP;
    }

#pragma unroll
    for (int o = 0; o < kCOUT; o++) out[(size_t)o * kNPF + p] = acc[o];
}

// ---------------- host launcher ----------------
extern "C" void kernel_launch(void* const* d_in, const int* in_sizes, int n_in,
                              void* d_out, int out_size, void* d_ws, size_t ws_size,
                              hipStream_t stream) {
    const float* x         = (const float*)d_in[0];
    const int*   enc_idx   = (const int*)d_in[1];
    const float* enc_vals  = (const float*)d_in[2];
    const float* enc_w     = (const float*)d_in[3];
    const int*   proc_idx  = (const int*)d_in[4];
    const float* proc_vals = (const float*)d_in[5];
    const float* lw        = (const float*)d_in[6];
    const float* gw        = (const float*)d_in[7];
    const float* Pw        = (const float*)d_in[8];
    const float* Pi        = (const float*)d_in[9];
    const float* m1        = (const float*)d_in[10];
    const float* m2        = (const float*)d_in[11];
    const float* ls        = (const float*)d_in[12];
    const int*   li0       = (const int*)d_in[13];
    const int*   li1       = (const int*)d_in[14];
    const float* lwt       = (const float*)d_in[15];
    const int*   oi0       = (const int*)d_in[16];
    const int*   oi1       = (const int*)d_in[17];
    const float* owt       = (const float*)d_in[18];
    const int*   dec_idx   = (const int*)d_in[19];
    const float* dec_vals  = (const float*)d_in[20];
    const float* dec_w     = (const float*)d_in[21];
    float* out = (float*)d_out;
    (void)dec_idx;

    float* ws = (float*)d_ws;
    size_t off = 0;
    auto alloc = [&](size_t n) { float* p = ws + off; off += n; return p; };
    float* h    = alloc((size_t)kCE * kNP);
    float* xre  = alloc((size_t)kCE * kHP * kM);
    float* xim  = alloc((size_t)kCE * kHP * kM);
    float* cre  = alloc((size_t)kCE * kL * kM);
    float* cim  = alloc((size_t)kCE * kL * kM);
    float* c2re = alloc((size_t)kCE * kL * kM);
    float* c2im = alloc((size_t)kCE * kL * kM);
    float* dx   = alloc((size_t)kCE * kNP);
    float* dx1  = alloc((size_t)kHD * kNP);
    float* fc   = alloc((size_t)kM * kWP);
    float* fs   = alloc((size_t)kM * kWP);
    float* ic   = alloc((size_t)kM * kWP);
    float* isn  = alloc((size_t)kM * kWP);
    float* PwT  = alloc((size_t)kL * kM * kHP);
    float* PiT  = alloc((size_t)kL * kM * kHP);
    float* dwT  = alloc((size_t)kCOUT * kCE * kK);
    (void)ws_size; (void)in_sizes; (void)n_in; (void)out_size;

    dim3 B(256);
    auto nb = [](long long n) { return dim3((unsigned)((n + 255) / 256)); };

    k_prep1<<<nb(kM * kWP), B, 0, stream>>>(fc, fs, ic, isn, dec_w, dwT);
    k_prep2<<<nb(2LL * kL * kM * kHP), B, 0, stream>>>(Pw, Pi, PwT, PiT);

    // encoder
    k_disco<kCIN, kCE, 8><<<nb((long long)kNP * 8), B, 0, stream>>>(
        x, kNPF, enc_idx, enc_vals, enc_w, h, kNP);

    for (int i = 0; i < kNL; i++) {
        if (i % 2 == 0) {
            const float* gwl = gw + (size_t)(i / 2) * kCE * kCE * kL;
            k_rfft<<<nb((long long)kCE * kHP * kM), B, 0, stream>>>(h, fc, fs, xre, xim);
            k_sht<<<nb((long long)kCE * kL * kM), B, 0, stream>>>(PwT, xre, xim, cre, cim);
            k_gmix<<<nb((long long)kCE * kL * kM), B, 0, stream>>>(gwl, cre, cim, c2re, c2im);
            k_isht<<<nb((long long)kCE * kHP * kM), B, 0, stream>>>(PiT, c2re, c2im, xre, xim);
            k_irfft<<<nb((long long)kCE * kHP * kWP), B, 0, stream>>>(xre, xim, ic, isn, dx);
        } else {
            const float* lwl = lw + (size_t)(i / 2) * kCE * kCE * kK;
            k_disco<kCE, kCE, 8><<<nb((long long)kNP * 8), B, 0, stream>>>(
                h, kNP, proc_idx, proc_vals, lwl, dx, kNP);
        }
        k_mlp1<<<nb((long long)kHD * kNP), B, 0, stream>>>(m1 + (size_t)i * kHD * kCE, dx, dx1);
        k_mlp2<<<nb((long long)kCE * kNP), B, 0, stream>>>(m2 + (size_t)i * kCE * kHD, ls + (size_t)i * kCE, dx1, h);
    }

    // decoder: per-point 3x3 stencil, direct from global, barrier-free
    k_dconv_d<<<nb((long long)kNPF), B, 0, stream>>>(h, dec_vals, dwT,
                                                     li0, li1, lwt, oi0, oi1, owt, out);
}